// Round 9
// baseline (4292.379 us; speedup 1.0000x reference)
//
#include <hip/hip_runtime.h>

#define T_ 1000

__device__ __forceinline__ float sigf(float x) { return 1.0f / (1.0f + __expf(-x)); }
__device__ __forceinline__ float tanh_fast(float x) { return 1.0f - 2.0f / (1.0f + __expf(2.0f * x)); }
__device__ __forceinline__ float dot4(float4 a, float4 b) {
  return a.x * b.x + a.y * b.y + a.z * b.z + a.w * b.w;
}
__device__ __forceinline__ unsigned short f2bf(float f) {
  unsigned u = __float_as_uint(f);
  u = (u + 0x7fffu + ((u >> 16) & 1u)) >> 16;  // RNE
  return (unsigned short)u;
}
__device__ __forceinline__ float bf2f(unsigned short h) {
  return __uint_as_float(((unsigned)h) << 16);
}
__device__ __forceinline__ float4 bf4_to_f4(ushort4 u) {
  float4 r;
  r.x = bf2f(u.x); r.y = bf2f(u.y); r.z = bf2f(u.z); r.w = bf2f(u.w);
  return r;
}

__global__ void bail_kernel(float* out, int n) {
  for (int i = threadIdx.x; i < n; i += 256) out[i] = 0.0f;
}

// ---------------- LN stats: per row (mu, rs) ----------------
__global__ __launch_bounds__(256) void ln_stats_kernel(const float* __restrict__ x,
                                                       float* __restrict__ mu_arr,
                                                       float* __restrict__ rs_arr) {
  const int lane = threadIdx.x & 63;
  const int w = threadIdx.x >> 6;
  const long row = (long)blockIdx.x * 4 + w;
  float v = (lane < 40) ? x[row * 40 + lane] : 0.0f;
  float s1 = v, s2 = v * v;
  for (int m = 32; m; m >>= 1) {
    s1 += __shfl_xor(s1, m, 64);
    s2 += __shfl_xor(s2, m, 64);
  }
  if (lane == 0) {
    const float mu = s1 * (1.0f / 40.0f);
    const float var = s2 * (1.0f / 40.0f) - mu * mu;
    mu_arr[row] = mu;
    rs_arr[row] = rsqrtf(var + 1e-5f);
  }
}

// ---------------- Layer-0 recurrence: 1024 threads, k-EIGHTH split ----------------
// lane: unit u = wave*8 + (lane>>3), octet p = tid&7. Weights/lane: Whh 64f + Wih 24f
// -> fits the hard 128-VGPR cap of 16-wave blocks (rounds 7/8 at 512 thr held 176
// weight floats in AGPRs: ~440 v_accvgpr_read/step/lane = the VALU inflation).
// h4f parity-double-buffered (read su&1, write su&1^1): race-free with 1 barrier/step.
__global__ __launch_bounds__(1024, 1) void rec0_kernel(
    const float* __restrict__ x,
    const float* __restrict__ mu_arr, const float* __restrict__ rs_arr,
    const float* __restrict__ ln_g, const float* __restrict__ ln_b,
    const float* __restrict__ Wih_f, const float* __restrict__ Whh_f,
    const float* __restrict__ bih_f, const float* __restrict__ bhh_f,
    const float* __restrict__ Wih_b, const float* __restrict__ Whh_b,
    const float* __restrict__ bih_b, const float* __restrict__ bhh_b,
    float* __restrict__ h0) {
  const int tid = threadIdx.x;
  const int u = (tid >> 6) * 8 + ((tid & 63) >> 3);  // 0..127
  const int p = tid & 7;                             // k-eighth
  const int brow = blockIdx.x & 127;
  const int dir = blockIdx.x >> 7;
  const float* __restrict__ Wih = dir ? Wih_b : Wih_f;
  const float* __restrict__ Whh = dir ? Whh_b : Whh_f;
  const float* __restrict__ bih = dir ? bih_b : bih_f;
  const float* __restrict__ bhh = dir ? bhh_b : bhh_f;

  // Whh: 4 gates x 4 float4 (k in [p*16, p*16+16)), rotated (ff+p)&3 for bank spread.
  float4 wh[4][4];
  float2 wi[4][3];  // LN-folded Wih over k in [p*6, p*6+6) of the 48-padded row
  float S1[4], bias[4];
#pragma unroll
  for (int g = 0; g < 4; ++g) {
    const int row = g * 128 + u;
    const float4* wr4 = (const float4*)(Whh + row * 128 + p * 16);
#pragma unroll
    for (int ff = 0; ff < 4; ++ff) wh[g][ff] = wr4[(ff + p) & 3];
    float s1p = 0.0f, s2p = 0.0f;
#pragma unroll
    for (int f = 0; f < 3; ++f) {
      float tmp[2];
#pragma unroll
      for (int e = 0; e < 2; ++e) {
        const int k = p * 6 + f * 2 + e;
        const float wv = (k < 40) ? Wih[row * 40 + k] : 0.0f;
        const float gk = (k < 40) ? ln_g[k] : 0.0f;
        const float bk = (k < 40) ? ln_b[k] : 0.0f;
        const float wf = wv * gk;
        tmp[e] = wf;
        s1p += wf;
        s2p += wv * bk;
      }
      wi[g][f] = make_float2(tmp[0], tmp[1]);
    }
    s1p += __shfl_xor(s1p, 1, 64); s1p += __shfl_xor(s1p, 2, 64); s1p += __shfl_xor(s1p, 4, 64);
    s2p += __shfl_xor(s2p, 1, 64); s2p += __shfl_xor(s2p, 2, 64); s2p += __shfl_xor(s2p, 4, 64);
    S1[g] = s1p;
    bias[g] = bih[g * 128 + u] + bhh[g * 128 + u] + s2p;
  }

  __shared__ float h4f[2][128];                  // parity double-buffer
  __shared__ __align__(16) float x_ring[2][8][48];
  __shared__ float mu_ring[2][8], rs_ring[2][8];
  __shared__ float hring[2][8][128];

  const int lr8 = tid / 40;
  const int lcol = tid - lr8 * 40;
  const long xbase = (long)brow * T_ * 40;
  const long mbase = (long)brow * T_;
  const long hbase = (long)brow * T_ * 256;

  if (tid < 128) h4f[0][tid] = 0.0f;
  if (tid < 128) {  // zero pad cols 40..47 of both x buffers (never rewritten)
    const int b = tid >> 6, r = (tid >> 3) & 7, cc = 40 + (tid & 7);
    x_ring[b][r][cc] = 0.0f;
  }
  if (tid < 320) {
    const int t = lr8;
    const int tt = dir ? (T_ - 1 - t) : t;
    x_ring[0][lr8][lcol] = x[xbase + (long)tt * 40 + lcol];
  } else if (tid < 328) {
    const int t = tid - 320;
    const int tt = dir ? (T_ - 1 - t) : t;
    mu_ring[0][t] = mu_arr[mbase + tt];
  } else if (tid < 336) {
    const int t = tid - 328;
    const int tt = dir ? (T_ - 1 - t) : t;
    rs_ring[0][t] = rs_arr[mbase + tt];
  }
  float c = 0.0f;
  float xpf = 0.0f, mupf = 0.0f, rspf = 0.0f;
  __syncthreads();

  for (int sb = 0; sb < 125; ++sb) {
    const int rb = sb & 1;
#pragma unroll
    for (int su = 0; su < 8; ++su) {
      const int rdq = su & 1, wrq = rdq ^ 1;  // 8 steps/group -> parity is compile-time
      if (su == 0) {
        if (sb + 1 < 125) {  // issue next-group prefetch into regs
          if (tid < 320) {
            const int t = (sb + 1) * 8 + lr8;
            const int tt = dir ? (T_ - 1 - t) : t;
            xpf = x[xbase + (long)tt * 40 + lcol];
          } else if (tid < 328) {
            const int t = (sb + 1) * 8 + (tid - 320);
            const int tt = dir ? (T_ - 1 - t) : t;
            mupf = mu_arr[mbase + tt];
          } else if (tid < 336) {
            const int t = (sb + 1) * 8 + (tid - 328);
            const int tt = dir ? (T_ - 1 - t) : t;
            rspf = rs_arr[mbase + tt];
          }
        }
        if (sb > 0) {  // bulk h-store of previous group (1024 values = 1/thread)
          const int v = tid >> 7, j = tid & 127;
          const int ts = (sb - 1) * 8 + v;
          const int te = dir ? (T_ - 1 - ts) : ts;
          h0[hbase + (long)te * 256 + dir * 128 + j] = hring[rb ^ 1][v][j];
        }
      }
      // ---- dot phase ----
      float a0 = 0.f, a1 = 0.f, a2 = 0.f, a3 = 0.f;
      const float4* h4v = (const float4*)h4f[rdq];
#pragma unroll
      for (int ff = 0; ff < 4; ++ff) {
        const float4 hv = h4v[p * 4 + ((ff + p) & 3)];
        a0 += dot4(hv, wh[0][ff]);
        a1 += dot4(hv, wh[1][ff]);
        a2 += dot4(hv, wh[2][ff]);
        a3 += dot4(hv, wh[3][ff]);
      }
      float x0 = 0.f, x1 = 0.f, x2 = 0.f, x3 = 0.f;
      const float2* xr2 = (const float2*)&x_ring[rb][su][p * 6];
#pragma unroll
      for (int f = 0; f < 3; ++f) {
        const float2 xv = xr2[f];
        x0 += wi[0][f].x * xv.x + wi[0][f].y * xv.y;
        x1 += wi[1][f].x * xv.x + wi[1][f].y * xv.y;
        x2 += wi[2][f].x * xv.x + wi[2][f].y * xv.y;
        x3 += wi[3][f].x * xv.x + wi[3][f].y * xv.y;
      }
      const float rs = rs_ring[rb][su];
      const float mu = mu_ring[rb][su];
      float pg[4];
      pg[0] = a0 + rs * x0;
      pg[1] = a1 + rs * x1;
      pg[2] = a2 + rs * x2;
      pg[3] = a3 + rs * x3;
#pragma unroll
      for (int g = 0; g < 4; ++g) {
        pg[g] += __shfl_xor(pg[g], 1, 64);
        pg[g] += __shfl_xor(pg[g], 2, 64);
        pg[g] += __shfl_xor(pg[g], 4, 64);
        pg[g] += bias[g] - rs * mu * S1[g];
      }
      const float ig = sigf(pg[0]);
      const float fg = sigf(pg[1]);
      const float gg = tanh_fast(pg[2]);
      const float og = sigf(pg[3]);
      c = fg * c + ig * gg;
      const float hv = og * tanh_fast(c);
      if (p == 0) { h4f[wrq][u] = hv; hring[rb][su][u] = hv; }
      if (su == 7 && sb + 1 < 125) {  // commit prefetched group to buffers rb^1
        if (tid < 320) x_ring[rb ^ 1][lr8][lcol] = xpf;
        else if (tid < 328) mu_ring[rb ^ 1][tid - 320] = mupf;
        else if (tid < 336) rs_ring[rb ^ 1][tid - 328] = rspf;
      }
      __syncthreads();
    }
  }
  {  // final group store (sb=124 -> ring 0)
    const int v = tid >> 7, j = tid & 127;
    const int ts = 124 * 8 + v;
    const int te = dir ? (T_ - 1 - ts) : ts;
    h0[hbase + (long)te * 256 + dir * 128 + j] = hring[0][v][j];
  }
}

// ---------------- Layer-1 recurrence: 1024 threads, k-eighth split, time-chunked ----------------
__global__ __launch_bounds__(1024, 1) void rec1_kernel(
    const float* __restrict__ xw_f, const float* __restrict__ xw_b,
    const float* __restrict__ Whh_f, const float* __restrict__ bih_f, const float* __restrict__ bhh_f,
    const float* __restrict__ Whh_b, const float* __restrict__ bih_b, const float* __restrict__ bhh_b,
    unsigned short* __restrict__ h1b, float* __restrict__ state,
    int Tc, int t0f, int t0b, int first) {
  const int tid = threadIdx.x;
  const int u = (tid >> 6) * 8 + ((tid & 63) >> 3);
  const int p = tid & 7;
  const int brow = blockIdx.x & 127;
  const int dir = blockIdx.x >> 7;
  const float* __restrict__ xw = dir ? xw_b : xw_f;
  const float* __restrict__ Whh = dir ? Whh_b : Whh_f;
  const float* __restrict__ bih = dir ? bih_b : bih_f;
  const float* __restrict__ bhh = dir ? bhh_b : bhh_f;
  const int t0 = dir ? t0b : t0f;

  float4 wh[4][4];
#pragma unroll
  for (int g = 0; g < 4; ++g) {
    const float4* wr4 = (const float4*)(Whh + (g * 128 + u) * 128 + p * 16);
#pragma unroll
    for (int ff = 0; ff < 4; ++ff) wh[g][ff] = wr4[(ff + p) & 3];
  }
  // lane p<4 owns gate-row p of unit u: adds xw + bias pre-reduce
  const int myrow = p * 128 + u;
  const float bias_p = (p < 4) ? (bih[myrow] + bhh[myrow]) : 0.0f;

  __shared__ float h4f[2][128];
  __shared__ float hring[2][8][128];
  float* sblk = state + (long)blockIdx.x * 256;
  float c = 0.0f;
  if (first) {
    if (tid < 128) h4f[0][tid] = 0.0f;
  } else {
    if (tid < 128) h4f[0][tid] = sblk[tid];
    c = sblk[128 + u];  // replicated per octet
  }
  const long gbase = (long)brow * Tc;
  float xr[8];
#pragma unroll
  for (int v = 0; v < 8; ++v) {
    xr[v] = 0.0f;
    if (p < 4 && v < Tc) {
      const int tr = dir ? (Tc - 1 - v) : v;
      xr[v] = xw[(gbase + tr) * 512 + myrow];
    }
  }
  __syncthreads();

  const int nSB = (Tc + 7) / 8;
  for (int sb = 0; sb < nSB; ++sb) {
    const int rb = sb & 1;
#pragma unroll
    for (int su = 0; su < 8; ++su) {
      const int s = sb * 8 + su;
      if (s >= Tc) break;  // uniform
      const int rdq = su & 1, wrq = rdq ^ 1;
      if (su == 0 && sb > 0) {  // bulk bf16 store of previous (full) group
        const int v = tid >> 7, j = tid & 127;
        const int s2 = (sb - 1) * 8 + v;
        const int tt = dir ? (Tc - 1 - s2) : s2;
        h1b[((long)brow * T_ + (t0 + tt)) * 256 + dir * 128 + j] = f2bf(hring[rb ^ 1][v][j]);
      }
      float a0 = 0.f, a1 = 0.f, a2 = 0.f, a3 = 0.f;
      const float4* h4v = (const float4*)h4f[rdq];
#pragma unroll
      for (int ff = 0; ff < 4; ++ff) {
        const float4 hv = h4v[p * 4 + ((ff + p) & 3)];
        a0 += dot4(hv, wh[0][ff]);
        a1 += dot4(hv, wh[1][ff]);
        a2 += dot4(hv, wh[2][ff]);
        a3 += dot4(hv, wh[3][ff]);
      }
      const float xin = xr[su] + bias_p;  // zero on p>=4
      float pg[4];
      pg[0] = a0 + ((p == 0) ? xin : 0.0f);
      pg[1] = a1 + ((p == 1) ? xin : 0.0f);
      pg[2] = a2 + ((p == 2) ? xin : 0.0f);
      pg[3] = a3 + ((p == 3) ? xin : 0.0f);
#pragma unroll
      for (int g = 0; g < 4; ++g) {
        pg[g] += __shfl_xor(pg[g], 1, 64);
        pg[g] += __shfl_xor(pg[g], 2, 64);
        pg[g] += __shfl_xor(pg[g], 4, 64);
      }
      const float ig = sigf(pg[0]);
      const float fg = sigf(pg[1]);
      const float gg = tanh_fast(pg[2]);
      const float og = sigf(pg[3]);
      c = fg * c + ig * gg;
      const float hv = og * tanh_fast(c);
      if (p == 0) { h4f[wrq][u] = hv; hring[rb][su][u] = hv; }
      if (su == 7) {  // refill xw for next group
#pragma unroll
        for (int v = 0; v < 8; ++v) {
          const int sn = s + 1 + v;
          xr[v] = 0.0f;
          if (p < 4 && sn < Tc) {
            const int tr = dir ? (Tc - 1 - sn) : sn;
            xr[v] = xw[(gbase + tr) * 512 + myrow];
          }
        }
      }
      __syncthreads();
    }
  }
  {  // final (possibly partial) group store
    const int sbL = (Tc - 1) >> 3;
    const int cnt = Tc - sbL * 8;
    const int rbL = sbL & 1;
    const int v = tid >> 7, j = tid & 127;
    if (v < cnt) {
      const int s2 = sbL * 8 + v;
      const int tt = dir ? (Tc - 1 - s2) : s2;
      h1b[((long)brow * T_ + (t0 + tt)) * 256 + dir * 128 + j] = f2bf(hring[rbL][v][j]);
    }
  }
  if (tid < 128) sblk[tid] = h4f[Tc & 1][tid];
  if (p == 0) sblk[128 + u] = c;
}

// ---------------- xw chunk GEMM: tile M=64 x N=128, K-step 32, micro 4x8 ----------------
// Liveness bounded by design (acc 32 regs, unroll-1 on kk/k4) -- see round-6 note.
__global__ __launch_bounds__(256, 2) void gemm_xw1(
    const float* __restrict__ h0,
    const float* __restrict__ Wf, const float* __restrict__ Wb,
    float* __restrict__ xwf, float* __restrict__ xwb,
    int Tc, int t0f, int t0b) {
  __shared__ float As[64 * 36];
  __shared__ float Bs[128 * 36];
  __shared__ int rowbase[64];
  const int tid = threadIdx.x;
  const int tx = tid & 15, ty = tid >> 4;
  const int r0 = blockIdx.x * 64;
  const int jt = blockIdx.y;
  const int dir = jt >> 2;
  const int nh = jt & 3;
  const float* __restrict__ W = dir ? Wb : Wf;
  float* __restrict__ out = dir ? xwb : xwf;
  const int jbase = nh * 128;
  const int t0 = dir ? t0b : t0f;

  if (tid < 64) {
    const int r = r0 + tid;
    const int br = r / Tc;
    rowbase[tid] = br * T_ + t0 + (r - br * Tc);
  }

  float4* As4 = (float4*)As;
  float4* Bs4 = (float4*)Bs;
  float acc[4][8] = {};
#pragma unroll 1
  for (int kk = 0; kk < 8; ++kk) {
    __syncthreads();
#pragma unroll
    for (int i = 0; i < 2; ++i) {
      const int q = tid + i * 256;
      const int row = q >> 3, k4 = q & 7;
      As4[row * 9 + k4] = *(const float4*)&h0[(long)rowbase[row] * 256 + kk * 32 + k4 * 4];
    }
#pragma unroll
    for (int i = 0; i < 4; ++i) {
      const int q = tid + i * 256;
      const int row = q >> 3, k4 = q & 7;
      Bs4[row * 9 + k4] = *(const float4*)&W[(long)(jbase + row) * 256 + kk * 32 + k4 * 4];
    }
    __syncthreads();
#pragma unroll 1
    for (int k4 = 0; k4 < 8; ++k4) {
      float4 av[4];
#pragma unroll
      for (int r = 0; r < 4; ++r) av[r] = As4[(ty * 4 + r) * 9 + k4];
#pragma unroll
      for (int c2 = 0; c2 < 8; ++c2) {
        const float4 bv = Bs4[(tx + 16 * c2) * 9 + k4];
#pragma unroll
        for (int r = 0; r < 4; ++r) acc[r][c2] += dot4(av[r], bv);
      }
    }
  }
#pragma unroll
  for (int r = 0; r < 4; ++r) {
    const long ob = (long)(r0 + ty * 4 + r) * 512 + jbase + tx;
#pragma unroll
    for (int c2 = 0; c2 < 8; ++c2) out[ob + c2 * 16] = acc[r][c2];
  }
}

// ---------------- attention scores ----------------
__global__ __launch_bounds__(256, 2) void score_kernel(
    const unsigned short* __restrict__ h1b, const float* __restrict__ W1,
    const float* __restrict__ b1, const float* __restrict__ w2,
    float* __restrict__ scores) {
  __shared__ float As[64 * 36];
  __shared__ float Bs[128 * 36];
  const int tid = threadIdx.x;
  const int tx = tid & 15, ty = tid >> 4;
  const long r0 = (long)blockIdx.x * 64;

  float4* As4 = (float4*)As;
  float4* Bs4 = (float4*)Bs;
  float acc[4][8] = {};
#pragma unroll 1
  for (int kk = 0; kk < 8; ++kk) {
    __syncthreads();
#pragma unroll
    for (int i = 0; i < 2; ++i) {
      const int q = tid + i * 256;
      const int row = q >> 3, k4 = q & 7;
      const ushort4 uv = *(const ushort4*)&h1b[(r0 + row) * 256 + kk * 32 + k4 * 4];
      As4[row * 9 + k4] = bf4_to_f4(uv);
    }
#pragma unroll
    for (int i = 0; i < 4; ++i) {
      const int q = tid + i * 256;
      const int row = q >> 3, k4 = q & 7;
      Bs4[row * 9 + k4] = *(const float4*)&W1[(long)row * 256 + kk * 32 + k4 * 4];
    }
    __syncthreads();
#pragma unroll 1
    for (int k4 = 0; k4 < 8; ++k4) {
      float4 av[4];
#pragma unroll
      for (int r = 0; r < 4; ++r) av[r] = As4[(ty * 4 + r) * 9 + k4];
#pragma unroll
      for (int c2 = 0; c2 < 8; ++c2) {
        const float4 bv = Bs4[(tx + 16 * c2) * 9 + k4];
#pragma unroll
        for (int r = 0; r < 4; ++r) acc[r][c2] += dot4(av[r], bv);
      }
    }
  }
#pragma unroll
  for (int r = 0; r < 4; ++r) {
    float s = 0.0f;
#pragma unroll
    for (int c2 = 0; c2 < 8; ++c2) {
      const int col = tx + 16 * c2;
      s += tanh_fast(acc[r][c2] + b1[col]) * w2[col];
    }
#pragma unroll
    for (int m = 1; m < 16; m <<= 1) s += __shfl_xor(s, m, 16);
    if (tx == 0) scores[r0 + ty * 4 + r] = s;
  }
}

// ---------------- softmax over T + ctx + MLP head ----------------
__global__ __launch_bounds__(256, 2) void head_kernel(
    const float* __restrict__ scores, const unsigned short* __restrict__ h1b,
    const float* __restrict__ fW1, const float* __restrict__ fb1,
    const float* __restrict__ fW2, const float* __restrict__ fb2,
    float* __restrict__ outp) {
  const int b = blockIdx.x, tid = threadIdx.x;
  __shared__ float wls[1000];
  __shared__ float red[8];
  __shared__ __align__(16) float ctx[256];
  __shared__ __align__(16) float hid[128];

  float sv[4];
  float mx = -1e30f;
#pragma unroll
  for (int i = 0; i < 4; ++i) {
    const int t = tid + i * 256;
    sv[i] = (t < 1000) ? scores[b * 1000 + t] : -1e30f;
    mx = fmaxf(mx, sv[i]);
  }
  for (int m = 32; m; m >>= 1) mx = fmaxf(mx, __shfl_xor(mx, m, 64));
  if ((tid & 63) == 0) red[tid >> 6] = mx;
  __syncthreads();
  mx = fmaxf(fmaxf(red[0], red[1]), fmaxf(red[2], red[3]));
  float se = 0.0f;
#pragma unroll
  for (int i = 0; i < 4; ++i) {
    const int t = tid + i * 256;
    if (t < 1000) {
      const float e = __expf(sv[i] - mx);
      wls[t] = e;
      se += e;
    }
  }
  for (int m = 32; m; m >>= 1) se += __shfl_xor(se, m, 64);
  if ((tid & 63) == 0) red[4 + (tid >> 6)] = se;
  __syncthreads();
  const float rinv = 1.0f / (red[4] + red[5] + red[6] + red[7]);

  float a = 0.0f;
  const unsigned short* hb = h1b + (long)b * T_ * 256 + tid;
  for (int t = 0; t < T_; ++t) a = fmaf(wls[t], bf2f(hb[t * 256]), a);
  ctx[tid] = a * rinv;
  __syncthreads();
  if (tid < 128) {
    float s = fb1[tid];
    const float4* wr = (const float4*)&fW1[tid * 256];
    const float4* cc = (const float4*)ctx;
#pragma unroll
    for (int f = 0; f < 64; ++f) s += dot4(wr[f], cc[f]);
    hid[tid] = fmaxf(s, 0.0f);
  }
  __syncthreads();
  if (tid < 8) {
    float s = fb2[tid];
    const float4* wr = (const float4*)&fW2[tid * 128];
    const float4* hh = (const float4*)hid;
#pragma unroll
    for (int f = 0; f < 32; ++f) s += dot4(wr[f], hh[f]);
    outp[b * 8 + tid] = s;
  }
}

extern "C" void kernel_launch(void* const* d_in, const int* in_sizes, int n_in,
                              void* d_out, int out_size, void* d_ws, size_t ws_size,
                              hipStream_t stream) {
  (void)in_sizes; (void)n_in; (void)out_size;
  const float* x       = (const float*)d_in[0];
  const float* ln_g    = (const float*)d_in[1];
  const float* ln_b    = (const float*)d_in[2];
  const float* Wih_f0  = (const float*)d_in[3];
  const float* Whh_f0  = (const float*)d_in[4];
  const float* bih_f0  = (const float*)d_in[5];
  const float* bhh_f0  = (const float*)d_in[6];
  const float* Wih_b0  = (const float*)d_in[7];
  const float* Whh_b0  = (const float*)d_in[8];
  const float* bih_b0  = (const float*)d_in[9];
  const float* bhh_b0  = (const float*)d_in[10];
  const float* Wih_f1  = (const float*)d_in[11];
  const float* Whh_f1  = (const float*)d_in[12];
  const float* bih_f1  = (const float*)d_in[13];
  const float* bhh_f1  = (const float*)d_in[14];
  const float* Wih_b1  = (const float*)d_in[15];
  const float* Whh_b1  = (const float*)d_in[16];
  const float* bih_b1  = (const float*)d_in[17];
  const float* bhh_b1  = (const float*)d_in[18];
  const float* attn_W1 = (const float*)d_in[19];
  const float* attn_b1 = (const float*)d_in[20];
  const float* attn_w2 = (const float*)d_in[21];
  const float* fc_W1   = (const float*)d_in[22];
  const float* fc_b1   = (const float*)d_in[23];
  const float* fc_W2   = (const float*)d_in[24];
  const float* fc_b2   = (const float*)d_in[25];

  char* base = (char*)d_ws;
  size_t off = 0;
  auto alloc = [&](size_t bytes) {
    char* ptr = base + off;
    off += (bytes + 255) & ~(size_t)255;
    return ptr;
  };
  float*          h0    = (float*)alloc(32768000ull * 4);          // 131.1 MB
  unsigned short* h1b   = (unsigned short*)alloc(32768000ull * 2); //  65.5 MB
  float*          state = (float*)alloc(65536ull * 4);
  float*          scor  = (float*)alloc(128000ull * 4);
  float*          mu_a  = (float*)alloc(128000ull * 4);
  float*          rs_a  = (float*)alloc(128000ull * 4);

  const size_t rem = (ws_size > off) ? (ws_size - off) : 0;
  static const int cands[16] = {1000, 500, 250, 200, 125, 100, 50, 40, 25, 20, 10, 8, 5, 4, 2, 1};
  int Tc = 0;
  for (int ci = 0; ci < 16; ++ci) {
    if (524288ull * (size_t)cands[ci] <= rem) { Tc = cands[ci]; break; }
  }
  if (Tc == 0) {
    bail_kernel<<<dim3(1), dim3(256), 0, stream>>>((float*)d_out, 1024);
    return;
  }
  float* xwf = (float*)(base + off);
  float* xwb = xwf + 65536L * Tc;

  ln_stats_kernel<<<dim3(32000), dim3(256), 0, stream>>>(x, mu_a, rs_a);
  rec0_kernel<<<dim3(256), dim3(1024), 0, stream>>>(x, mu_a, rs_a, ln_g, ln_b,
                                                    Wih_f0, Whh_f0, bih_f0, bhh_f0,
                                                    Wih_b0, Whh_b0, bih_b0, bhh_b0, h0);
  const int nch = T_ / Tc;
  for (int ch = 0; ch < nch; ++ch) {
    const int t0f = ch * Tc;
    const int t0b = T_ - (ch + 1) * Tc;
    gemm_xw1<<<dim3(2 * Tc, 8), dim3(256), 0, stream>>>(h0, Wih_f1, Wih_b1, xwf, xwb, Tc, t0f, t0b);
    rec1_kernel<<<dim3(256), dim3(1024), 0, stream>>>(xwf, xwb, Whh_f1, bih_f1, bhh_f1,
                                                      Whh_b1, bih_b1, bhh_b1, h1b, state,
                                                      Tc, t0f, t0b, (ch == 0) ? 1 : 0);
  }
  score_kernel<<<dim3(2000), dim3(256), 0, stream>>>(h1b, attn_W1, attn_b1, attn_w2, scor);
  head_kernel<<<dim3(128), dim3(256), 0, stream>>>(scor, h1b, fc_W1, fc_b1, fc_W2, fc_b2,
                                                   (float*)d_out);
}

// Round 10
// 3172.920 us; speedup vs baseline: 1.3528x; 1.3528x over previous
//
#include <hip/hip_runtime.h>

#define T_ 1000

typedef float v2f __attribute__((ext_vector_type(2)));

__device__ __forceinline__ float sigf(float x) { return 1.0f / (1.0f + __expf(-x)); }
__device__ __forceinline__ float tanh_fast(float x) { return 1.0f - 2.0f / (1.0f + __expf(2.0f * x)); }
__device__ __forceinline__ float dot4(float4 a, float4 b) {
  return a.x * b.x + a.y * b.y + a.z * b.z + a.w * b.w;
}
__device__ __forceinline__ void pkfma(v2f& acc, float4 w, float4 v) {
  v2f wl; wl[0] = w.x; wl[1] = w.y;
  v2f wh; wh[0] = w.z; wh[1] = w.w;
  v2f vl; vl[0] = v.x; vl[1] = v.y;
  v2f vh; vh[0] = v.z; vh[1] = v.w;
  acc += wl * vl;
  acc += wh * vh;
}
__device__ __forceinline__ unsigned short f2bf(float f) {
  unsigned u = __float_as_uint(f);
  u = (u + 0x7fffu + ((u >> 16) & 1u)) >> 16;  // RNE
  return (unsigned short)u;
}
__device__ __forceinline__ float bf2f(unsigned short h) {
  return __uint_as_float(((unsigned)h) << 16);
}
__device__ __forceinline__ float4 bf4_to_f4(ushort4 u) {
  float4 r;
  r.x = bf2f(u.x); r.y = bf2f(u.y); r.z = bf2f(u.z); r.w = bf2f(u.w);
  return r;
}

__global__ void bail_kernel(float* out, int n) {
  for (int i = threadIdx.x; i < n; i += 256) out[i] = 0.0f;
}

// ---------------- LN stats: per row (mu, rs) ----------------
__global__ __launch_bounds__(256) void ln_stats_kernel(const float* __restrict__ x,
                                                       float* __restrict__ mu_arr,
                                                       float* __restrict__ rs_arr) {
  const int lane = threadIdx.x & 63;
  const int w = threadIdx.x >> 6;
  const long row = (long)blockIdx.x * 4 + w;
  float v = (lane < 40) ? x[row * 40 + lane] : 0.0f;
  float s1 = v, s2 = v * v;
  for (int m = 32; m; m >>= 1) {
    s1 += __shfl_xor(s1, m, 64);
    s2 += __shfl_xor(s2, m, 64);
  }
  if (lane == 0) {
    const float mu = s1 * (1.0f / 40.0f);
    const float var = s2 * (1.0f / 40.0f) - mu * mu;
    mu_arr[row] = mu;
    rs_arr[row] = rsqrtf(var + 1e-5f);
  }
}

// ---------------- Layer-0 recurrence: quad-mapped k-split, 1 barrier/step ----------------
// lane: unit u = wave*16 + (lane>>2), k-quarter p = lane&3. Weights/lane: 176 floats.
// amdgpu_waves_per_eu(2,2): pins 2 waves/EU (1 block/CU, grid=256=CU count) -> 256-VGPR
// budget, so weights live in arch VGPRs (the default 2-block/CU heuristic gave only
// 65536/512=128 regs -> weights in AGPRs -> ~2.5x VALU inflation, rounds 7-9).
// h4f parity double-buffer (read su&1, write su&1^1): race-free with 1 barrier/step.
__global__ __launch_bounds__(512) __attribute__((amdgpu_waves_per_eu(2, 2))) void rec0_kernel(
    const float* __restrict__ x,
    const float* __restrict__ mu_arr, const float* __restrict__ rs_arr,
    const float* __restrict__ ln_g, const float* __restrict__ ln_b,
    const float* __restrict__ Wih_f, const float* __restrict__ Whh_f,
    const float* __restrict__ bih_f, const float* __restrict__ bhh_f,
    const float* __restrict__ Wih_b, const float* __restrict__ Whh_b,
    const float* __restrict__ bih_b, const float* __restrict__ bhh_b,
    float* __restrict__ h0) {
  const int tid = threadIdx.x;
  const int u = (tid >> 6) * 16 + ((tid & 63) >> 2);
  const int p = tid & 3;
  const int brow = blockIdx.x & 127;
  const int dir = blockIdx.x >> 7;
  const float* __restrict__ Wih = dir ? Wih_b : Wih_f;
  const float* __restrict__ Whh = dir ? Whh_b : Whh_f;
  const float* __restrict__ bih = dir ? bih_b : bih_f;
  const float* __restrict__ bhh = dir ? bhh_b : bhh_f;

  // Whh fragments pre-rotated so h4 reads hit bank-disjoint quads.
  float4 wh[4][8];
  float4 wi[4][3];
  float S1[4], bias[4];
#pragma unroll
  for (int g = 0; g < 4; ++g) {
    const int row = g * 128 + u;
    const float4* wr = (const float4*)(Whh + row * 128 + p * 32);
#pragma unroll
    for (int ff = 0; ff < 8; ++ff) wh[g][ff] = wr[(ff + 2 * p) & 7];
    float s1p = 0.0f, s2p = 0.0f;
#pragma unroll
    for (int f = 0; f < 3; ++f) {
      float tmp[4];
#pragma unroll
      for (int e = 0; e < 4; ++e) {
        const int k = p * 12 + f * 4 + e;
        const float wv = (k < 40) ? Wih[row * 40 + k] : 0.0f;
        const float gk = (k < 40) ? ln_g[k] : 0.0f;
        const float bk = (k < 40) ? ln_b[k] : 0.0f;
        const float wf = wv * gk;
        tmp[e] = wf;
        s1p += wf;
        s2p += wv * bk;
      }
      wi[g][f] = make_float4(tmp[0], tmp[1], tmp[2], tmp[3]);
    }
    s1p += __shfl_xor(s1p, 1, 64); s1p += __shfl_xor(s1p, 2, 64);
    s2p += __shfl_xor(s2p, 1, 64); s2p += __shfl_xor(s2p, 2, 64);
    S1[g] = s1p;
    bias[g] = bih[g * 128 + u] + bhh[g * 128 + u] + s2p;
  }

  __shared__ float h4f[2][128];                 // parity double-buffer
  __shared__ __align__(16) float x_ring[2][8][48];
  __shared__ float mu_ring[2][8], rs_ring[2][8];
  __shared__ float hring[2][8][128];

  const int lr8 = tid / 40;
  const int lcol = tid - lr8 * 40;
  const long xbase = (long)brow * T_ * 40;
  const long mbase = (long)brow * T_;
  const long hbase = (long)brow * T_ * 256;

  if (tid < 128) h4f[0][tid] = 0.0f;
  if (tid < 128) {  // zero pad cols 40..47 of both x buffers (never rewritten)
    const int b = tid >> 6, r = (tid >> 3) & 7, cc = 40 + (tid & 7);
    x_ring[b][r][cc] = 0.0f;
  }
  if (tid < 320) {
    const int t = lr8;
    const int tt = dir ? (T_ - 1 - t) : t;
    x_ring[0][lr8][lcol] = x[xbase + (long)tt * 40 + lcol];
  } else if (tid < 328) {
    const int t = tid - 320;
    const int tt = dir ? (T_ - 1 - t) : t;
    mu_ring[0][t] = mu_arr[mbase + tt];
  } else if (tid < 336) {
    const int t = tid - 328;
    const int tt = dir ? (T_ - 1 - t) : t;
    rs_ring[0][t] = rs_arr[mbase + tt];
  }
  float c = 0.0f;
  float xpf = 0.0f, mupf = 0.0f, rspf = 0.0f;
  __syncthreads();

  for (int sb = 0; sb < 125; ++sb) {
    const int rb = sb & 1;
#pragma unroll
    for (int su = 0; su < 8; ++su) {
      const int rdq = su & 1, wrq = rdq ^ 1;  // compile-time parity per unrolled step
      if (su == 0) {
        if (sb + 1 < 125) {  // issue next-group prefetch into regs
          if (tid < 320) {
            const int t = (sb + 1) * 8 + lr8;
            const int tt = dir ? (T_ - 1 - t) : t;
            xpf = x[xbase + (long)tt * 40 + lcol];
          } else if (tid < 328) {
            const int t = (sb + 1) * 8 + (tid - 320);
            const int tt = dir ? (T_ - 1 - t) : t;
            mupf = mu_arr[mbase + tt];
          } else if (tid < 336) {
            const int t = (sb + 1) * 8 + (tid - 328);
            const int tt = dir ? (T_ - 1 - t) : t;
            rspf = rs_arr[mbase + tt];
          }
        }
        if (sb > 0) {  // bulk h-store of previous group
#pragma unroll
          for (int e = 0; e < 2; ++e) {
            const int idx = tid + e * 512;
            const int v = idx >> 7, j = idx & 127;
            const int ts = (sb - 1) * 8 + v;
            const int te = dir ? (T_ - 1 - ts) : ts;
            h0[hbase + (long)te * 256 + dir * 128 + j] = hring[rb ^ 1][v][j];
          }
        }
      }
      // ---- dot phase (packed-f32 accumulators) ----
      v2f hacc[4], xacc[4];
#pragma unroll
      for (int g = 0; g < 4; ++g) { hacc[g] = 0.0f; xacc[g] = 0.0f; }
      const float4* h4v = (const float4*)h4f[rdq];
#pragma unroll
      for (int ff = 0; ff < 8; ++ff) {
        const float4 hv = h4v[p * 8 + ((ff + 2 * p) & 7)];
        pkfma(hacc[0], wh[0][ff], hv);
        pkfma(hacc[1], wh[1][ff], hv);
        pkfma(hacc[2], wh[2][ff], hv);
        pkfma(hacc[3], wh[3][ff], hv);
      }
      const float4* xr4 = (const float4*)x_ring[rb][su];
#pragma unroll
      for (int f = 0; f < 3; ++f) {
        const float4 xv = xr4[p * 3 + f];
        pkfma(xacc[0], wi[0][f], xv);
        pkfma(xacc[1], wi[1][f], xv);
        pkfma(xacc[2], wi[2][f], xv);
        pkfma(xacc[3], wi[3][f], xv);
      }
      const float rs = rs_ring[rb][su];
      const float mu = mu_ring[rb][su];
      float pg[4];
#pragma unroll
      for (int g = 0; g < 4; ++g) {
        pg[g] = (hacc[g][0] + hacc[g][1]) + rs * (xacc[g][0] + xacc[g][1]);
        pg[g] += __shfl_xor(pg[g], 1, 64);
        pg[g] += __shfl_xor(pg[g], 2, 64);
        pg[g] += bias[g] - rs * mu * S1[g];
      }
      const float ig = sigf(pg[0]);
      const float fg = sigf(pg[1]);
      const float gg = tanh_fast(pg[2]);
      const float og = sigf(pg[3]);
      c = fg * c + ig * gg;
      const float hv = og * tanh_fast(c);
      if (p == 0) { h4f[wrq][u] = hv; hring[rb][su][u] = hv; }
      if (su == 7 && sb + 1 < 125) {  // commit prefetched group to buffers rb^1
        if (tid < 320) x_ring[rb ^ 1][lr8][lcol] = xpf;
        else if (tid < 328) mu_ring[rb ^ 1][tid - 320] = mupf;
        else if (tid < 336) rs_ring[rb ^ 1][tid - 328] = rspf;
      }
      __syncthreads();
    }
  }
#pragma unroll
  for (int e = 0; e < 2; ++e) {  // final group store (sb=124 -> ring 0)
    const int idx = tid + e * 512;
    const int v = idx >> 7, j = idx & 127;
    const int ts = 124 * 8 + v;
    const int te = dir ? (T_ - 1 - ts) : ts;
    h0[hbase + (long)te * 256 + dir * 128 + j] = hring[0][v][j];
  }
}

// ---------------- Layer-1 recurrence: quad-mapped, 1 barrier/step, time-chunked ----------------
__global__ __launch_bounds__(512) __attribute__((amdgpu_waves_per_eu(2, 2))) void rec1_kernel(
    const float* __restrict__ xw_f, const float* __restrict__ xw_b,
    const float* __restrict__ Whh_f, const float* __restrict__ bih_f, const float* __restrict__ bhh_f,
    const float* __restrict__ Whh_b, const float* __restrict__ bih_b, const float* __restrict__ bhh_b,
    unsigned short* __restrict__ h1b, float* __restrict__ state,
    int Tc, int t0f, int t0b, int first) {
  const int tid = threadIdx.x;
  const int u = (tid >> 6) * 16 + ((tid & 63) >> 2);
  const int p = tid & 3;
  const int brow = blockIdx.x & 127;
  const int dir = blockIdx.x >> 7;
  const float* __restrict__ xw = dir ? xw_b : xw_f;
  const float* __restrict__ Whh = dir ? Whh_b : Whh_f;
  const float* __restrict__ bih = dir ? bih_b : bih_f;
  const float* __restrict__ bhh = dir ? bhh_b : bhh_f;
  const int t0 = dir ? t0b : t0f;

  float4 wh[4][8];
#pragma unroll
  for (int g = 0; g < 4; ++g) {
    const float4* wr = (const float4*)(Whh + (g * 128 + u) * 128 + p * 32);
#pragma unroll
    for (int ff = 0; ff < 8; ++ff) wh[g][ff] = wr[(ff + 2 * p) & 7];
  }
  const int myrow = p * 128 + u;
  const float bias_p = bih[myrow] + bhh[myrow];

  __shared__ float h4f[2][128];
  __shared__ float hring[2][8][128];
  float* sblk = state + (long)blockIdx.x * 256;
  float c = 0.0f;
  if (first) {
    if (tid < 128) h4f[0][tid] = 0.0f;
  } else {
    if (tid < 128) h4f[0][tid] = sblk[tid];
    c = sblk[128 + u];  // replicated per quad
  }
  const long gbase = (long)brow * Tc;
  float xr[8];
#pragma unroll
  for (int v = 0; v < 8; ++v) {
    xr[v] = 0.0f;
    if (v < Tc) {
      const int tr = dir ? (Tc - 1 - v) : v;
      xr[v] = xw[(gbase + tr) * 512 + myrow];
    }
  }
  __syncthreads();

  const int nSB = (Tc + 7) / 8;
  for (int sb = 0; sb < nSB; ++sb) {
    const int rb = sb & 1;
#pragma unroll
    for (int su = 0; su < 8; ++su) {
      const int s = sb * 8 + su;
      if (s >= Tc) break;  // uniform
      const int rdq = su & 1, wrq = rdq ^ 1;
      if (su == 0 && sb > 0) {  // bulk bf16 store of previous (full) group
#pragma unroll
        for (int e = 0; e < 2; ++e) {
          const int idx = tid + e * 512;
          const int v = idx >> 7, j = idx & 127;
          const int s2 = (sb - 1) * 8 + v;
          const int tt = dir ? (Tc - 1 - s2) : s2;
          h1b[((long)brow * T_ + (t0 + tt)) * 256 + dir * 128 + j] = f2bf(hring[rb ^ 1][v][j]);
        }
      }
      v2f hacc[4];
#pragma unroll
      for (int g = 0; g < 4; ++g) hacc[g] = 0.0f;
      const float4* h4v = (const float4*)h4f[rdq];
#pragma unroll
      for (int ff = 0; ff < 8; ++ff) {
        const float4 hv = h4v[p * 8 + ((ff + 2 * p) & 7)];
        pkfma(hacc[0], wh[0][ff], hv);
        pkfma(hacc[1], wh[1][ff], hv);
        pkfma(hacc[2], wh[2][ff], hv);
        pkfma(hacc[3], wh[3][ff], hv);
      }
      const float xin = xr[su] + bias_p;
      float pg[4];
#pragma unroll
      for (int g = 0; g < 4; ++g) {
        pg[g] = hacc[g][0] + hacc[g][1] + ((p == g) ? xin : 0.0f);
        pg[g] += __shfl_xor(pg[g], 1, 64);
        pg[g] += __shfl_xor(pg[g], 2, 64);
      }
      const float ig = sigf(pg[0]);
      const float fg = sigf(pg[1]);
      const float gg = tanh_fast(pg[2]);
      const float og = sigf(pg[3]);
      c = fg * c + ig * gg;
      const float hv = og * tanh_fast(c);
      if (p == 0) { h4f[wrq][u] = hv; hring[rb][su][u] = hv; }
      if (su == 7) {  // refill xw for next group
#pragma unroll
        for (int v = 0; v < 8; ++v) {
          const int sn = s + 1 + v;
          xr[v] = 0.0f;
          if (sn < Tc) {
            const int tr = dir ? (Tc - 1 - sn) : sn;
            xr[v] = xw[(gbase + tr) * 512 + myrow];
          }
        }
      }
      __syncthreads();
    }
  }
  {  // final (possibly partial) group store
    const int sbL = (Tc - 1) >> 3;
    const int cnt = Tc - sbL * 8;
    const int rbL = sbL & 1;
#pragma unroll
    for (int e = 0; e < 2; ++e) {
      const int idx = tid + e * 512;
      const int v = idx >> 7, j = idx & 127;
      if (v < cnt) {
        const int s2 = sbL * 8 + v;
        const int tt = dir ? (Tc - 1 - s2) : s2;
        h1b[((long)brow * T_ + (t0 + tt)) * 256 + dir * 128 + j] = f2bf(hring[rbL][v][j]);
      }
    }
  }
  if (tid < 128) sblk[tid] = h4f[Tc & 1][tid];  // last write buffer = ((Tc-1)&1)^1 = Tc&1
  if (p == 0) sblk[128 + u] = c;
}

// ---------------- xw chunk GEMM: tile M=64 x N=128, K-step 32, micro 4x8 ----------------
// Liveness bounded by design (acc 32 regs, unroll-1 on kk/k4) -- see round-6 note.
__global__ __launch_bounds__(256, 2) void gemm_xw1(
    const float* __restrict__ h0,
    const float* __restrict__ Wf, const float* __restrict__ Wb,
    float* __restrict__ xwf, float* __restrict__ xwb,
    int Tc, int t0f, int t0b) {
  __shared__ float As[64 * 36];
  __shared__ float Bs[128 * 36];
  __shared__ int rowbase[64];
  const int tid = threadIdx.x;
  const int tx = tid & 15, ty = tid >> 4;
  const int r0 = blockIdx.x * 64;
  const int jt = blockIdx.y;
  const int dir = jt >> 2;
  const int nh = jt & 3;
  const float* __restrict__ W = dir ? Wb : Wf;
  float* __restrict__ out = dir ? xwb : xwf;
  const int jbase = nh * 128;
  const int t0 = dir ? t0b : t0f;

  if (tid < 64) {
    const int r = r0 + tid;
    const int br = r / Tc;
    rowbase[tid] = br * T_ + t0 + (r - br * Tc);
  }

  float4* As4 = (float4*)As;
  float4* Bs4 = (float4*)Bs;
  float acc[4][8] = {};
#pragma unroll 1
  for (int kk = 0; kk < 8; ++kk) {
    __syncthreads();
#pragma unroll
    for (int i = 0; i < 2; ++i) {
      const int q = tid + i * 256;
      const int row = q >> 3, k4 = q & 7;
      As4[row * 9 + k4] = *(const float4*)&h0[(long)rowbase[row] * 256 + kk * 32 + k4 * 4];
    }
#pragma unroll
    for (int i = 0; i < 4; ++i) {
      const int q = tid + i * 256;
      const int row = q >> 3, k4 = q & 7;
      Bs4[row * 9 + k4] = *(const float4*)&W[(long)(jbase + row) * 256 + kk * 32 + k4 * 4];
    }
    __syncthreads();
#pragma unroll 1
    for (int k4 = 0; k4 < 8; ++k4) {
      float4 av[4];
#pragma unroll
      for (int r = 0; r < 4; ++r) av[r] = As4[(ty * 4 + r) * 9 + k4];
#pragma unroll
      for (int c2 = 0; c2 < 8; ++c2) {
        const float4 bv = Bs4[(tx + 16 * c2) * 9 + k4];
#pragma unroll
        for (int r = 0; r < 4; ++r) acc[r][c2] += dot4(av[r], bv);
      }
    }
  }
#pragma unroll
  for (int r = 0; r < 4; ++r) {
    const long ob = (long)(r0 + ty * 4 + r) * 512 + jbase + tx;
#pragma unroll
    for (int c2 = 0; c2 < 8; ++c2) out[ob + c2 * 16] = acc[r][c2];
  }
}

// ---------------- attention scores ----------------
__global__ __launch_bounds__(256, 2) void score_kernel(
    const unsigned short* __restrict__ h1b, const float* __restrict__ W1,
    const float* __restrict__ b1, const float* __restrict__ w2,
    float* __restrict__ scores) {
  __shared__ float As[64 * 36];
  __shared__ float Bs[128 * 36];
  const int tid = threadIdx.x;
  const int tx = tid & 15, ty = tid >> 4;
  const long r0 = (long)blockIdx.x * 64;

  float4* As4 = (float4*)As;
  float4* Bs4 = (float4*)Bs;
  float acc[4][8] = {};
#pragma unroll 1
  for (int kk = 0; kk < 8; ++kk) {
    __syncthreads();
#pragma unroll
    for (int i = 0; i < 2; ++i) {
      const int q = tid + i * 256;
      const int row = q >> 3, k4 = q & 7;
      const ushort4 uv = *(const ushort4*)&h1b[(r0 + row) * 256 + kk * 32 + k4 * 4];
      As4[row * 9 + k4] = bf4_to_f4(uv);
    }
#pragma unroll
    for (int i = 0; i < 4; ++i) {
      const int q = tid + i * 256;
      const int row = q >> 3, k4 = q & 7;
      Bs4[row * 9 + k4] = *(const float4*)&W1[(long)row * 256 + kk * 32 + k4 * 4];
    }
    __syncthreads();
#pragma unroll 1
    for (int k4 = 0; k4 < 8; ++k4) {
      float4 av[4];
#pragma unroll
      for (int r = 0; r < 4; ++r) av[r] = As4[(ty * 4 + r) * 9 + k4];
#pragma unroll
      for (int c2 = 0; c2 < 8; ++c2) {
        const float4 bv = Bs4[(tx + 16 * c2) * 9 + k4];
#pragma unroll
        for (int r = 0; r < 4; ++r) acc[r][c2] += dot4(av[r], bv);
      }
    }
  }
#pragma unroll
  for (int r = 0; r < 4; ++r) {
    float s = 0.0f;
#pragma unroll
    for (int c2 = 0; c2 < 8; ++c2) {
      const int col = tx + 16 * c2;
      s += tanh_fast(acc[r][c2] + b1[col]) * w2[col];
    }
#pragma unroll
    for (int m = 1; m < 16; m <<= 1) s += __shfl_xor(s, m, 16);
    if (tx == 0) scores[r0 + ty * 4 + r] = s;
  }
}

// ---------------- softmax over T + ctx + MLP head ----------------
__global__ __launch_bounds__(256, 2) void head_kernel(
    const float* __restrict__ scores, const unsigned short* __restrict__ h1b,
    const float* __restrict__ fW1, const float* __restrict__ fb1,
    const float* __restrict__ fW2, const float* __restrict__ fb2,
    float* __restrict__ outp) {
  const int b = blockIdx.x, tid = threadIdx.x;
  __shared__ float wls[1000];
  __shared__ float red[8];
  __shared__ __align__(16) float ctx[256];
  __shared__ __align__(16) float hid[128];

  float sv[4];
  float mx = -1e30f;
#pragma unroll
  for (int i = 0; i < 4; ++i) {
    const int t = tid + i * 256;
    sv[i] = (t < 1000) ? scores[b * 1000 + t] : -1e30f;
    mx = fmaxf(mx, sv[i]);
  }
  for (int m = 32; m; m >>= 1) mx = fmaxf(mx, __shfl_xor(mx, m, 64));
  if ((tid & 63) == 0) red[tid >> 6] = mx;
  __syncthreads();
  mx = fmaxf(fmaxf(red[0], red[1]), fmaxf(red[2], red[3]));
  float se = 0.0f;
#pragma unroll
  for (int i = 0; i < 4; ++i) {
    const int t = tid + i * 256;
    if (t < 1000) {
      const float e = __expf(sv[i] - mx);
      wls[t] = e;
      se += e;
    }
  }
  for (int m = 32; m; m >>= 1) se += __shfl_xor(se, m, 64);
  if ((tid & 63) == 0) red[4 + (tid >> 6)] = se;
  __syncthreads();
  const float rinv = 1.0f / (red[4] + red[5] + red[6] + red[7]);

  float a = 0.0f;
  const unsigned short* hb = h1b + (long)b * T_ * 256 + tid;
  for (int t = 0; t < T_; ++t) a = fmaf(wls[t], bf2f(hb[t * 256]), a);
  ctx[tid] = a * rinv;
  __syncthreads();
  if (tid < 128) {
    float s = fb1[tid];
    const float4* wr = (const float4*)&fW1[tid * 256];
    const float4* cc = (const float4*)ctx;
#pragma unroll
    for (int f = 0; f < 64; ++f) s += dot4(wr[f], cc[f]);
    hid[tid] = fmaxf(s, 0.0f);
  }
  __syncthreads();
  if (tid < 8) {
    float s = fb2[tid];
    const float4* wr = (const float4*)&fW2[tid * 128];
    const float4* hh = (const float4*)hid;
#pragma unroll
    for (int f = 0; f < 32; ++f) s += dot4(wr[f], hh[f]);
    outp[b * 8 + tid] = s;
  }
}

extern "C" void kernel_launch(void* const* d_in, const int* in_sizes, int n_in,
                              void* d_out, int out_size, void* d_ws, size_t ws_size,
                              hipStream_t stream) {
  (void)in_sizes; (void)n_in; (void)out_size;
  const float* x       = (const float*)d_in[0];
  const float* ln_g    = (const float*)d_in[1];
  const float* ln_b    = (const float*)d_in[2];
  const float* Wih_f0  = (const float*)d_in[3];
  const float* Whh_f0  = (const float*)d_in[4];
  const float* bih_f0  = (const float*)d_in[5];
  const float* bhh_f0  = (const float*)d_in[6];
  const float* Wih_b0  = (const float*)d_in[7];
  const float* Whh_b0  = (const float*)d_in[8];
  const float* bih_b0  = (const float*)d_in[9];
  const float* bhh_b0  = (const float*)d_in[10];
  const float* Wih_f1  = (const float*)d_in[11];
  const float* Whh_f1  = (const float*)d_in[12];
  const float* bih_f1  = (const float*)d_in[13];
  const float* bhh_f1  = (const float*)d_in[14];
  const float* Wih_b1  = (const float*)d_in[15];
  const float* Whh_b1  = (const float*)d_in[16];
  const float* bih_b1  = (const float*)d_in[17];
  const float* bhh_b1  = (const float*)d_in[18];
  const float* attn_W1 = (const float*)d_in[19];
  const float* attn_b1 = (const float*)d_in[20];
  const float* attn_w2 = (const float*)d_in[21];
  const float* fc_W1   = (const float*)d_in[22];
  const float* fc_b1   = (const float*)d_in[23];
  const float* fc_W2   = (const float*)d_in[24];
  const float* fc_b2   = (const float*)d_in[25];

  char* base = (char*)d_ws;
  size_t off = 0;
  auto alloc = [&](size_t bytes) {
    char* ptr = base + off;
    off += (bytes + 255) & ~(size_t)255;
    return ptr;
  };
  float*          h0    = (float*)alloc(32768000ull * 4);          // 131.1 MB
  unsigned short* h1b   = (unsigned short*)alloc(32768000ull * 2); //  65.5 MB
  float*          state = (float*)alloc(65536ull * 4);
  float*          scor  = (float*)alloc(128000ull * 4);
  float*          mu_a  = (float*)alloc(128000ull * 4);
  float*          rs_a  = (float*)alloc(128000ull * 4);

  const size_t rem = (ws_size > off) ? (ws_size - off) : 0;
  static const int cands[16] = {1000, 500, 250, 200, 125, 100, 50, 40, 25, 20, 10, 8, 5, 4, 2, 1};
  int Tc = 0;
  for (int ci = 0; ci < 16; ++ci) {
    if (524288ull * (size_t)cands[ci] <= rem) { Tc = cands[ci]; break; }
  }
  if (Tc == 0) {
    bail_kernel<<<dim3(1), dim3(256), 0, stream>>>((float*)d_out, 1024);
    return;
  }
  float* xwf = (float*)(base + off);
  float* xwb = xwf + 65536L * Tc;

  ln_stats_kernel<<<dim3(32000), dim3(256), 0, stream>>>(x, mu_a, rs_a);
  rec0_kernel<<<dim3(256), dim3(512), 0, stream>>>(x, mu_a, rs_a, ln_g, ln_b,
                                                   Wih_f0, Whh_f0, bih_f0, bhh_f0,
                                                   Wih_b0, Whh_b0, bih_b0, bhh_b0, h0);
  const int nch = T_ / Tc;
  for (int ch = 0; ch < nch; ++ch) {
    const int t0f = ch * Tc;
    const int t0b = T_ - (ch + 1) * Tc;
    gemm_xw1<<<dim3(2 * Tc, 8), dim3(256), 0, stream>>>(h0, Wih_f1, Wih_b1, xwf, xwb, Tc, t0f, t0b);
    rec1_kernel<<<dim3(256), dim3(512), 0, stream>>>(xwf, xwb, Whh_f1, bih_f1, bhh_f1,
                                                     Whh_b1, bih_b1, bhh_b1, h1b, state,
                                                     Tc, t0f, t0b, (ch == 0) ? 1 : 0);
  }
  score_kernel<<<dim3(2000), dim3(256), 0, stream>>>(h1b, attn_W1, attn_b1, attn_w2, scor);
  head_kernel<<<dim3(128), dim3(256), 0, stream>>>(scor, h1b, fc_W1, fc_b1, fc_W2, fc_b2,
                                                   (float*)d_out);
}